// Round 23
// baseline (245.552 us; speedup 1.0000x reference)
//
#include <hip/hip_runtime.h>
#include <hip/hip_bf16.h>

#define C2 340
#define HID 170
#define NB 4
#define HGT 256
#define WID 256
#define HW (HGT*WID)
#define BAND 128

typedef unsigned short u16;
typedef unsigned int u32;
typedef float f32x4 __attribute__((ext_vector_type(4)));
typedef short s16x8 __attribute__((ext_vector_type(8)));

__device__ __forceinline__ float bf2f(u16 u) {
  union { u32 i; float f; } v; v.i = ((u32)u) << 16; return v.f;
}
__device__ __forceinline__ u16 f2bf(float f) {
  union { float f; u32 i; } v; v.f = f;
  u32 x = v.i;
  return (u16)((x + 0x7fffu + ((x >> 16) & 1u)) >> 16);
}

// exact GELU via branchless A&S 7.1.26 erf (|err| <= 1.5e-7, below bf16 quantum)
// validated correct in rounds 16/18/19/20/21/22 (passed, absmax 0.046875)
__device__ __forceinline__ float gelu(float v) {
  const float u = v * 0.70710678118654752f;
  const float ax = fabsf(u);
  const float t = __builtin_amdgcn_rcpf(__builtin_fmaf(0.3275911f, ax, 1.f));
  float p = __builtin_fmaf(1.061405429f, t, -1.453152027f);
  p = __builtin_fmaf(p, t, 1.421413741f);
  p = __builtin_fmaf(p, t, -0.284496736f);
  p = __builtin_fmaf(p, t, 0.254829592f);
  const float e = __builtin_amdgcn_exp2f(-1.4426950408889634f * ax * ax);
  float er = 1.f - p * t * e;
  er = copysignf(er, u);
  return 0.5f * v * (1.f + er);
}

__device__ const float COSTAB[8] = {1.f, 0.70710678118654752f, 0.f, -0.70710678118654752f,
                                    -1.f, -0.70710678118654752f, 0.f, 0.70710678118654752f};

// ------- merged weight prepass: mfrag (blocks 0..339), wfrag (340), wofrag (341) -------
__global__ __launch_bounds__(256) void k_prep(const float* __restrict__ w_in,
                                              const float* __restrict__ w_out,
                                              const float* __restrict__ fw,
                                              u16* __restrict__ wf,
                                              u16* __restrict__ wof,
                                              u16* __restrict__ mf) {
  __shared__ float kern[64];
  const int blk = blockIdx.x;
  if (blk < C2) {
    const int c = blk;
    if (threadIdx.x < 64) {
      const int a = threadIdx.x >> 3, bb = threadIdx.x & 7;
      float acc = 0.f;
      for (int u = 0; u < 8; ++u)
        for (int v = 0; v < 8; ++v) {
          const float wv = (v <= 4) ? fw[c*40 + u*5 + v]
                                    : fw[c*40 + ((8-u)&7)*5 + (8-v)];
          acc += wv * COSTAB[(u*a + v*bb) & 7];
        }
      kern[threadIdx.x] = acc * (1.f/64.f);
    }
    __syncthreads();
    #pragma unroll
    for (int q = 0; q < 16; ++q) {
      const int e = q * 256 + threadIdx.x;
      const int r = e & 7;
      const int l = (e >> 3) & 63;
      const int sb = e >> 9;
      const int s = sb & 1, nblk = sb >> 1;
      const int k = s*32 + ((l >> 4) << 3) + r;
      const int a = k >> 3, bcol = k & 7;
      const int n = nblk*16 + (l & 15);
      const int i = n >> 3, j = n & 7;
      mf[(size_t)c * 4096 + e] = f2bf(kern[(((i - a) & 7) << 3) + ((j - bcol) & 7)]);
    }
  } else if (blk == C2) {
    for (int e = threadIdx.x; e < 22*2*64*8; e += 256) {
      const int r = e & 7;
      const int l = (e >> 3) & 63;
      const int ts = e >> 9;
      const int s = ts & 1, t = ts >> 1;
      const int m = t*16 + (l & 15);
      const int k = s*32 + ((l >> 4) << 3) + r;
      wf[e] = (m < C2) ? f2bf(w_in[m*64 + k]) : (u16)0;
    }
  } else {
    for (int e = threadIdx.x; e < 4*6*64*8; e += 256) {
      const int r = e & 7;
      const int l = (e >> 3) & 63;
      const int mk = e >> 9;
      const int kc = mk % 6, mt = mk / 6;
      const int m = mt*16 + (l & 15);
      const int k = kc*32 + ((l >> 4) << 3) + r;
      wof[e] = (k < HID) ? f2bf(w_out[m*HID + k]) : (u16)0;
    }
  }
}

// ---------------- K1: project_in (64 -> 340) via MFMA; m-tile split across 2 blocks ----------------
__global__ __launch_bounds__(256) void k_projin2(const float* __restrict__ x,
                                                 const u16* __restrict__ wf,
                                                 u16* __restrict__ mid) {
  __shared__ __align__(16) u16 st[2][16][264];     // 16,896 B double-buffered tile
  const int sp = blockIdx.x & 1;                   // m-tile half: tiles sp*11 .. sp*11+10
  const int rest = blockIdx.x >> 1;
  const int b = rest >> 8;
  const int pix_blk = (rest & 255) << 8;           // 256 px per block
  const int w = threadIdx.x >> 6;
  const int lane = threadIdx.x & 63;
  const int lm = lane & 15, lh = lane >> 4;
  const int pix0 = pix_blk + w*64;

  s16x8 Bf[4][2];                                  // 4 pixel groups x 2 ksteps
  {
    const float* xp = x + (size_t)b * 64 * HW + pix0;
    #pragma unroll
    for (int g = 0; g < 4; ++g)
      #pragma unroll
      for (int s = 0; s < 2; ++s) {
        s16x8 t;
        #pragma unroll
        for (int r = 0; r < 8; ++r) {
          const int ch = s*32 + lh*8 + r;
          t[r] = (short)f2bf(xp[(size_t)ch * HW + g*16 + lm]);
        }
        Bf[g][s] = t;
      }
  }
  u16* mp = mid + (size_t)b * C2 * HW + pix_blk;
  const int ch_rd = threadIdx.x >> 4;
  const int seg = threadIdx.x & 15;
  const int t0 = sp * 11;
  for (int t = t0; t < t0 + 11; ++t) {
    const int cur = t & 1;
    const s16x8 A0 = *(const s16x8*)(wf + ((t*2 + 0)*64 + lane)*8);
    const s16x8 A1 = *(const s16x8*)(wf + ((t*2 + 1)*64 + lane)*8);
    f32x4 ac[4];
    #pragma unroll
    for (int g = 0; g < 4; ++g) {
      ac[g] = (f32x4){0.f,0.f,0.f,0.f};
      ac[g] = __builtin_amdgcn_mfma_f32_16x16x32_bf16(A0, Bf[g][0], ac[g], 0,0,0);
      ac[g] = __builtin_amdgcn_mfma_f32_16x16x32_bf16(A1, Bf[g][1], ac[g], 0,0,0);
    }
    #pragma unroll
    for (int g = 0; g < 4; ++g)
      #pragma unroll
      for (int r = 0; r < 4; ++r)
        st[cur][lh*4 + r][w*64 + g*16 + lm] = f2bf(ac[g][r]);
    __syncthreads();                               // the ONLY barrier per iteration
    const int ch = t*16 + ch_rd;
    if (ch < C2) {
      u16* dst = mp + (size_t)ch * HW + seg*16;
      *(uint4*)dst       = *(const uint4*)&st[cur][ch_rd][seg*16];
      *(uint4*)(dst + 8) = *(const uint4*)&st[cur][ch_rd][seg*16 + 8];
    }
  }
}

// ======= FUSED: pconv (MFMA -> LDS) + dwconv3x3 + GELU; double-buffered, half-band =======
// block = (b, gate-channel c, 64-row half-band); 512 threads = 8 waves; 4 x 16-row tiles.
__global__ __launch_bounds__(512) void k_pcgate(const u16* __restrict__ mid,
                                                const u16* __restrict__ mf,
                                                const float* __restrict__ w_dw,
                                                u16* __restrict__ gbuf, int hb) {
  __shared__ __align__(16) u16 st[2][2][18][272];  // 39,168 B (double buffer)
  const int sub = blockIdx.x & 1;                  // 64-row half of the band
  const int rest = blockIdx.x >> 1;
  const int c = rest % HID;
  const int b = rest / HID;
  const int P0 = (hb + sub*64) >> 3;

  const int w = threadIdx.x >> 6;
  const int lane = threadIdx.x & 63;
  const int lm = lane & 15, lh = lane >> 4;
  const int ch2 = w >> 2;                          // 0: channel c, 1: channel c+HID
  const int wl = w & 3;                            // wave role
  const int prow_sub = wl >> 1;                    // patch-row within tile
  const int phalf = wl & 1;                        // 16-patch column half
  const int ch = c + ch2*HID;
  const int colbase = (phalf*16 + lh*4)*8 + (lm & 7) + 8;   // +8 col pad

  // one-time zero init of BOTH buffers (covers pads; B writes only cols 8..263)
  for (int i = threadIdx.x; i < 2*2*18*34; i += 512)
    ((uint4*)st)[i] = make_uint4(0,0,0,0);

  s16x8 Bc[4][2];
  const u16* mfc = mf + (size_t)ch * 4096;
  #pragma unroll
  for (int nb = 0; nb < 4; ++nb)
    #pragma unroll
    for (int ks = 0; ks < 2; ++ks)
      Bc[nb][ks] = *(const s16x8*)(mfc + ((nb*2 + ks)*64 + lane)*8);
  const u16* chan = mid + (size_t)(b*C2 + ch) * HW;
  const float* wd1 = w_dw + c * 9;
  const float* wd2 = w_dw + (c + HID) * 9;
  __syncthreads();

  for (int it = 0; it < 4; ++it) {
    const int cur = it & 1;
    u16 (* __restrict__ sb)[18][272] = st[cur];
    // --- B: pconv MFMA -> sb rows 0..17 ---
    {
      const int py = P0 + it*2 + prow_sub;
      const u16* aptr = chan + (size_t)(py*8 + lh)*WID + (phalf*16 + lm)*8;
      const s16x8 A0 = *(const s16x8*)(aptr);
      const s16x8 A1 = *(const s16x8*)(aptr + 4*WID);
      const int rowb = 1 + prow_sub*8 + (lm >> 3);
      #pragma unroll
      for (int nb = 0; nb < 4; ++nb) {
        f32x4 acc = {0.f,0.f,0.f,0.f};
        acc = __builtin_amdgcn_mfma_f32_16x16x32_bf16(A0, Bc[nb][0], acc, 0,0,0);
        acc = __builtin_amdgcn_mfma_f32_16x16x32_bf16(A1, Bc[nb][1], acc, 0,0,0);
        #pragma unroll
        for (int r = 0; r < 4; ++r)
          sb[ch2][rowb + nb*2][colbase + r*8] = f2bf(acc[r]);
      }
    }
    if (wl < 2) {                                  // halo row 17: first row of patch py2
      const int py2 = P0 + it*2 + 2;
      f32x4 acc = {0.f,0.f,0.f,0.f};
      if (py2 < 32) {
        const u16* ap = chan + (size_t)(py2*8 + lh)*WID + (phalf*16 + lm)*8;
        const s16x8 A0 = *(const s16x8*)(ap);
        const s16x8 A1 = *(const s16x8*)(ap + 4*WID);
        acc = __builtin_amdgcn_mfma_f32_16x16x32_bf16(A0, Bc[0][0], acc, 0,0,0);
        acc = __builtin_amdgcn_mfma_f32_16x16x32_bf16(A1, Bc[0][1], acc, 0,0,0);
      }
      if ((lm >> 3) == 0) {                        // patch row 0 lanes cover full row
        #pragma unroll
        for (int r = 0; r < 4; ++r)
          sb[ch2][17][colbase + r*8] = f2bf(acc[r]);
      }
    } else {                                       // halo row 0: last row of patch pym
      const int pym = P0 + it*2 - 1;
      f32x4 acc = {0.f,0.f,0.f,0.f};
      if (pym >= 0) {
        const u16* ap = chan + (size_t)(pym*8 + lh)*WID + (phalf*16 + lm)*8;
        const s16x8 A0 = *(const s16x8*)(ap);
        const s16x8 A1 = *(const s16x8*)(ap + 4*WID);
        acc = __builtin_amdgcn_mfma_f32_16x16x32_bf16(A0, Bc[3][0], acc, 0,0,0);
        acc = __builtin_amdgcn_mfma_f32_16x16x32_bf16(A1, Bc[3][1], acc, 0,0,0);
      }
      if ((lm >> 3) == 1) {                        // patch row 7 lanes cover full row
        #pragma unroll
        for (int r = 0; r < 4; ++r)
          sb[ch2][0][colbase + r*8] = f2bf(acc[r]);
      }
    }
    __syncthreads();                               // the ONLY barrier per iteration
    // --- C: dwconv 3x3 + GELU gate from sb; next iter writes the other buffer ---
    {
      const int rg = threadIdx.x >> 5;             // output row 0..15
      const int px0 = (threadIdx.x & 31) * 8;
      float ax[8], ay[8];
      #pragma unroll
      for (int p = 0; p < 8; ++p) { ax[p] = 0.f; ay[p] = 0.f; }
      #pragma unroll
      for (int wr = 0; wr < 3; ++wr) {
        const u16* r1 = &sb[0][rg + wr][px0];
        const u16* r2 = &sb[1][rg + wr][px0];
        const s16x8 L1 = *(const s16x8*)r1, M1 = *(const s16x8*)(r1 + 8), R1 = *(const s16x8*)(r1 + 16);
        const s16x8 L2 = *(const s16x8*)r2, M2 = *(const s16x8*)(r2 + 8), R2 = *(const s16x8*)(r2 + 16);
        float cx[10], cy[10];
        cx[0] = bf2f((u16)L1[7]);  cy[0] = bf2f((u16)L2[7]);
        #pragma unroll
        for (int p = 0; p < 8; ++p) { cx[p+1] = bf2f((u16)M1[p]); cy[p+1] = bf2f((u16)M2[p]); }
        cx[9] = bf2f((u16)R1[0]);  cy[9] = bf2f((u16)R2[0]);
        const float w1a = wd1[wr*3+0], w1b = wd1[wr*3+1], w1c = wd1[wr*3+2];
        const float w2a = wd2[wr*3+0], w2b = wd2[wr*3+1], w2c = wd2[wr*3+2];
        #pragma unroll
        for (int p = 0; p < 8; ++p) {
          ax[p] += w1a*cx[p] + w1b*cx[p+1] + w1c*cx[p+2];
          ay[p] += w2a*cy[p] + w2b*cy[p+1] + w2c*cy[p+2];
        }
      }
      u32 pk[4];
      #pragma unroll
      for (int p2 = 0; p2 < 4; ++p2) {
        const float g0 = gelu(ax[2*p2])   * ay[2*p2];
        const float g1 = gelu(ax[2*p2+1]) * ay[2*p2+1];
        pk[p2] = (u32)f2bf(g0) | ((u32)f2bf(g1) << 16);
      }
      u16* gp = gbuf + (((size_t)(b*HID + c)) * BAND + (size_t)(sub*64 + it*16 + rg)) * WID + px0;
      *(uint4*)gp = make_uint4(pk[0], pk[1], pk[2], pk[3]);
    }
  }
}

// ------- K3b: project_out (170 -> 64) via MFMA -------
__global__ __launch_bounds__(256) void k_projout2(const u16* __restrict__ gbuf,
                                                  const u16* __restrict__ wof,
                                                  float* __restrict__ out, int hb) {
  const int b = blockIdx.x >> 7;
  const int p0 = (blockIdx.x & 127) << 8;
  const int w = threadIdx.x >> 6;
  const int lane = threadIdx.x & 63;
  const int lm = lane & 15, lh = lane >> 4;
  const size_t BW = (size_t)BAND * WID;
  const u16* gb = gbuf + (size_t)b * HID * BW + p0 + w*64 + lm;

  f32x4 acc[4][4];
  #pragma unroll
  for (int mt = 0; mt < 4; ++mt)
    #pragma unroll
    for (int ng = 0; ng < 4; ++ng)
      acc[mt][ng] = (f32x4){0.f,0.f,0.f,0.f};

  #pragma unroll
  for (int kc = 0; kc < 6; ++kc) {
    s16x8 A[4];
    #pragma unroll
    for (int mt = 0; mt < 4; ++mt)
      A[mt] = *(const s16x8*)(wof + ((mt*6 + kc)*64 + lane)*8);
    #pragma unroll
    for (int ng = 0; ng < 4; ++ng) {
      s16x8 Bf;
      #pragma unroll
      for (int r = 0; r < 8; ++r) {
        int c = kc*32 + lh*8 + r;
        if (kc == 5) c = min(c, HID - 1);
        Bf[r] = (short)gb[(size_t)c * BW + ng*16];
      }
      #pragma unroll
      for (int mt = 0; mt < 4; ++mt)
        acc[mt][ng] = __builtin_amdgcn_mfma_f32_16x16x32_bf16(A[mt], Bf, acc[mt][ng], 0,0,0);
    }
  }
  float* ob = out + (size_t)b * 64 * HW + (size_t)hb * WID + p0 + w*64 + lm;
  #pragma unroll
  for (int mt = 0; mt < 4; ++mt)
    #pragma unroll
    for (int ng = 0; ng < 4; ++ng)
      #pragma unroll
      for (int r = 0; r < 4; ++r)
        ob[(size_t)(mt*16 + lh*4 + r) * HW + ng*16] = acc[mt][ng][r];
}

extern "C" void kernel_launch(void* const* d_in, const int* in_sizes, int n_in,
                              void* d_out, int out_size, void* d_ws, size_t ws_size,
                              hipStream_t stream) {
  const float* x     = (const float*)d_in[0];
  const float* w_in  = (const float*)d_in[1];
  const float* w_dw  = (const float*)d_in[2];
  const float* fw    = (const float*)d_in[3];
  const float* w_out = (const float*)d_in[4];
  float* out = (float*)d_out;

  char* ws = (char*)d_ws;
  u16* mid    = (u16*)ws;                                  // 178,257,920 B (pre-conv)
  u16* gbuf   = (u16*)(ws + 178257920);                    // 44,564,480 B
  u16* wof    = (u16*)(ws + 178257920 + 44564480);         // 24,576 B
  u16* mfrag  = (u16*)(ws + 178257920 + 44564480 + 43520); // 2,785,280 B
  u16* wfrag  = (u16*)(ws + 178257920 + 44564480 + 43520 + 2785280); // 45,056 B

  k_prep<<<C2 + 2, 256, 0, stream>>>(w_in, w_out, fw, wfrag, wof, mfrag);
  k_projin2<<<NB*256*2, 256, 0, stream>>>(x, wfrag, mid);
  for (int sb = 0; sb < 2; ++sb) {
    const int hb = sb * BAND;
    k_pcgate<<<NB*HID*2, 512, 0, stream>>>(mid, mfrag, w_dw, gbuf, hb);
    k_projout2<<<NB*BAND, 256, 0, stream>>>(gbuf, wof, out, hb);
  }
}

// Round 24
// 222.603 us; speedup vs baseline: 1.1031x; 1.1031x over previous
//
#include <hip/hip_runtime.h>
#include <hip/hip_bf16.h>

#define C2 340
#define HID 170
#define NB 4
#define HGT 256
#define WID 256
#define HW (HGT*WID)
#define BAND 128

typedef unsigned short u16;
typedef unsigned int u32;
typedef float f32x4 __attribute__((ext_vector_type(4)));
typedef short s16x8 __attribute__((ext_vector_type(8)));

__device__ __forceinline__ float bf2f(u16 u) {
  union { u32 i; float f; } v; v.i = ((u32)u) << 16; return v.f;
}
__device__ __forceinline__ u16 f2bf(float f) {
  union { float f; u32 i; } v; v.f = f;
  u32 x = v.i;
  return (u16)((x + 0x7fffu + ((x >> 16) & 1u)) >> 16);
}

// exact GELU via branchless A&S 7.1.26 erf (|err| <= 1.5e-7, below bf16 quantum)
// validated correct in rounds 16/18/19/20/21/22 (passed, absmax 0.046875)
__device__ __forceinline__ float gelu(float v) {
  const float u = v * 0.70710678118654752f;
  const float ax = fabsf(u);
  const float t = __builtin_amdgcn_rcpf(__builtin_fmaf(0.3275911f, ax, 1.f));
  float p = __builtin_fmaf(1.061405429f, t, -1.453152027f);
  p = __builtin_fmaf(p, t, 1.421413741f);
  p = __builtin_fmaf(p, t, -0.284496736f);
  p = __builtin_fmaf(p, t, 0.254829592f);
  const float e = __builtin_amdgcn_exp2f(-1.4426950408889634f * ax * ax);
  float er = 1.f - p * t * e;
  er = copysignf(er, u);
  return 0.5f * v * (1.f + er);
}

__device__ const float COSTAB[8] = {1.f, 0.70710678118654752f, 0.f, -0.70710678118654752f,
                                    -1.f, -0.70710678118654752f, 0.f, 0.70710678118654752f};

// ------- merged weight prepass: mfrag (blocks 0..339), wfrag (340), wofrag (341) -------
__global__ __launch_bounds__(256) void k_prep(const float* __restrict__ w_in,
                                              const float* __restrict__ w_out,
                                              const float* __restrict__ fw,
                                              u16* __restrict__ wf,
                                              u16* __restrict__ wof,
                                              u16* __restrict__ mf) {
  __shared__ float kern[64];
  const int blk = blockIdx.x;
  if (blk < C2) {
    const int c = blk;
    if (threadIdx.x < 64) {
      const int a = threadIdx.x >> 3, bb = threadIdx.x & 7;
      float acc = 0.f;
      for (int u = 0; u < 8; ++u)
        for (int v = 0; v < 8; ++v) {
          const float wv = (v <= 4) ? fw[c*40 + u*5 + v]
                                    : fw[c*40 + ((8-u)&7)*5 + (8-v)];
          acc += wv * COSTAB[(u*a + v*bb) & 7];
        }
      kern[threadIdx.x] = acc * (1.f/64.f);
    }
    __syncthreads();
    #pragma unroll
    for (int q = 0; q < 16; ++q) {
      const int e = q * 256 + threadIdx.x;
      const int r = e & 7;
      const int l = (e >> 3) & 63;
      const int sb = e >> 9;
      const int s = sb & 1, nblk = sb >> 1;
      const int k = s*32 + ((l >> 4) << 3) + r;
      const int a = k >> 3, bcol = k & 7;
      const int n = nblk*16 + (l & 15);
      const int i = n >> 3, j = n & 7;
      mf[(size_t)c * 4096 + e] = f2bf(kern[(((i - a) & 7) << 3) + ((j - bcol) & 7)]);
    }
  } else if (blk == C2) {
    for (int e = threadIdx.x; e < 22*2*64*8; e += 256) {
      const int r = e & 7;
      const int l = (e >> 3) & 63;
      const int ts = e >> 9;
      const int s = ts & 1, t = ts >> 1;
      const int m = t*16 + (l & 15);
      const int k = s*32 + ((l >> 4) << 3) + r;
      wf[e] = (m < C2) ? f2bf(w_in[m*64 + k]) : (u16)0;
    }
  } else {
    for (int e = threadIdx.x; e < 4*6*64*8; e += 256) {
      const int r = e & 7;
      const int l = (e >> 3) & 63;
      const int mk = e >> 9;
      const int kc = mk % 6, mt = mk / 6;
      const int m = mt*16 + (l & 15);
      const int k = kc*32 + ((l >> 4) << 3) + r;
      wof[e] = (k < HID) ? f2bf(w_out[m*HID + k]) : (u16)0;
    }
  }
}

// ---------------- K1: project_in (64 -> 340) via MFMA; double-buffered epilogue ----------------
__global__ __launch_bounds__(256) void k_projin2(const float* __restrict__ x,
                                                 const u16* __restrict__ wf,
                                                 u16* __restrict__ mid) {
  __shared__ __align__(16) u16 st[2][16][264];     // 16,896 B double-buffered tile
  const int b = blockIdx.x >> 8;
  const int pix_blk = (blockIdx.x & 255) << 8;     // 256 px per block
  const int w = threadIdx.x >> 6;
  const int lane = threadIdx.x & 63;
  const int lm = lane & 15, lh = lane >> 4;
  const int pix0 = pix_blk + w*64;

  s16x8 Bf[4][2];                                  // 4 pixel groups x 2 ksteps
  {
    const float* xp = x + (size_t)b * 64 * HW + pix0;
    #pragma unroll
    for (int g = 0; g < 4; ++g)
      #pragma unroll
      for (int s = 0; s < 2; ++s) {
        s16x8 t;
        #pragma unroll
        for (int r = 0; r < 8; ++r) {
          const int ch = s*32 + lh*8 + r;
          t[r] = (short)f2bf(xp[(size_t)ch * HW + g*16 + lm]);
        }
        Bf[g][s] = t;
      }
  }
  u16* mp = mid + (size_t)b * C2 * HW + pix_blk;
  const int ch_rd = threadIdx.x >> 4;
  const int seg = threadIdx.x & 15;
  for (int t = 0; t < 22; ++t) {
    const int cur = t & 1;
    const s16x8 A0 = *(const s16x8*)(wf + ((t*2 + 0)*64 + lane)*8);
    const s16x8 A1 = *(const s16x8*)(wf + ((t*2 + 1)*64 + lane)*8);
    f32x4 ac[4];
    #pragma unroll
    for (int g = 0; g < 4; ++g) {
      ac[g] = (f32x4){0.f,0.f,0.f,0.f};
      ac[g] = __builtin_amdgcn_mfma_f32_16x16x32_bf16(A0, Bf[g][0], ac[g], 0,0,0);
      ac[g] = __builtin_amdgcn_mfma_f32_16x16x32_bf16(A1, Bf[g][1], ac[g], 0,0,0);
    }
    #pragma unroll
    for (int g = 0; g < 4; ++g)
      #pragma unroll
      for (int r = 0; r < 4; ++r)
        st[cur][lh*4 + r][w*64 + g*16 + lm] = f2bf(ac[g][r]);
    __syncthreads();                               // the ONLY barrier per iteration
    const int ch = t*16 + ch_rd;
    if (ch < C2) {
      u16* dst = mp + (size_t)ch * HW + seg*16;
      *(uint4*)dst       = *(const uint4*)&st[cur][ch_rd][seg*16];
      *(uint4*)(dst + 8) = *(const uint4*)&st[cur][ch_rd][seg*16 + 8];
    }
  }
}

// ======= FUSED: pconv (MFMA -> LDS) + dwconv3x3 + GELU; double-buffered, half-band =======
// block = (b, gate-channel c, 64-row half-band); 512 threads = 8 waves; 4 x 16-row tiles.
__global__ __launch_bounds__(512) void k_pcgate(const u16* __restrict__ mid,
                                                const u16* __restrict__ mf,
                                                const float* __restrict__ w_dw,
                                                u16* __restrict__ gbuf, int hb) {
  __shared__ __align__(16) u16 st[2][2][18][272];  // 39,168 B (double buffer)
  const int sub = blockIdx.x & 1;                  // 64-row half of the band
  const int rest = blockIdx.x >> 1;
  const int c = rest % HID;
  const int b = rest / HID;
  const int P0 = (hb + sub*64) >> 3;

  const int w = threadIdx.x >> 6;
  const int lane = threadIdx.x & 63;
  const int lm = lane & 15, lh = lane >> 4;
  const int ch2 = w >> 2;                          // 0: channel c, 1: channel c+HID
  const int wl = w & 3;                            // wave role
  const int prow_sub = wl >> 1;                    // patch-row within tile
  const int phalf = wl & 1;                        // 16-patch column half
  const int ch = c + ch2*HID;
  const int colbase = (phalf*16 + lh*4)*8 + (lm & 7) + 8;   // +8 col pad

  // one-time zero init of BOTH buffers (covers pads; B writes only cols 8..263)
  for (int i = threadIdx.x; i < 2*2*18*34; i += 512)
    ((uint4*)st)[i] = make_uint4(0,0,0,0);

  s16x8 Bc[4][2];
  const u16* mfc = mf + (size_t)ch * 4096;
  #pragma unroll
  for (int nb = 0; nb < 4; ++nb)
    #pragma unroll
    for (int ks = 0; ks < 2; ++ks)
      Bc[nb][ks] = *(const s16x8*)(mfc + ((nb*2 + ks)*64 + lane)*8);
  const u16* chan = mid + (size_t)(b*C2 + ch) * HW;
  const float* wd1 = w_dw + c * 9;
  const float* wd2 = w_dw + (c + HID) * 9;
  __syncthreads();

  for (int it = 0; it < 4; ++it) {
    const int cur = it & 1;
    u16 (* __restrict__ sb)[18][272] = st[cur];
    // --- B: pconv MFMA -> sb rows 0..17 ---
    {
      const int py = P0 + it*2 + prow_sub;
      const u16* aptr = chan + (size_t)(py*8 + lh)*WID + (phalf*16 + lm)*8;
      const s16x8 A0 = *(const s16x8*)(aptr);
      const s16x8 A1 = *(const s16x8*)(aptr + 4*WID);
      const int rowb = 1 + prow_sub*8 + (lm >> 3);
      #pragma unroll
      for (int nb = 0; nb < 4; ++nb) {
        f32x4 acc = {0.f,0.f,0.f,0.f};
        acc = __builtin_amdgcn_mfma_f32_16x16x32_bf16(A0, Bc[nb][0], acc, 0,0,0);
        acc = __builtin_amdgcn_mfma_f32_16x16x32_bf16(A1, Bc[nb][1], acc, 0,0,0);
        #pragma unroll
        for (int r = 0; r < 4; ++r)
          sb[ch2][rowb + nb*2][colbase + r*8] = f2bf(acc[r]);
      }
    }
    if (wl < 2) {                                  // halo row 17: first row of patch py2
      const int py2 = P0 + it*2 + 2;
      f32x4 acc = {0.f,0.f,0.f,0.f};
      if (py2 < 32) {
        const u16* ap = chan + (size_t)(py2*8 + lh)*WID + (phalf*16 + lm)*8;
        const s16x8 A0 = *(const s16x8*)(ap);
        const s16x8 A1 = *(const s16x8*)(ap + 4*WID);
        acc = __builtin_amdgcn_mfma_f32_16x16x32_bf16(A0, Bc[0][0], acc, 0,0,0);
        acc = __builtin_amdgcn_mfma_f32_16x16x32_bf16(A1, Bc[0][1], acc, 0,0,0);
      }
      if ((lm >> 3) == 0) {                        // patch row 0 lanes cover full row
        #pragma unroll
        for (int r = 0; r < 4; ++r)
          sb[ch2][17][colbase + r*8] = f2bf(acc[r]);
      }
    } else {                                       // halo row 0: last row of patch pym
      const int pym = P0 + it*2 - 1;
      f32x4 acc = {0.f,0.f,0.f,0.f};
      if (pym >= 0) {
        const u16* ap = chan + (size_t)(pym*8 + lh)*WID + (phalf*16 + lm)*8;
        const s16x8 A0 = *(const s16x8*)(ap);
        const s16x8 A1 = *(const s16x8*)(ap + 4*WID);
        acc = __builtin_amdgcn_mfma_f32_16x16x32_bf16(A0, Bc[3][0], acc, 0,0,0);
        acc = __builtin_amdgcn_mfma_f32_16x16x32_bf16(A1, Bc[3][1], acc, 0,0,0);
      }
      if ((lm >> 3) == 1) {                        // patch row 7 lanes cover full row
        #pragma unroll
        for (int r = 0; r < 4; ++r)
          sb[ch2][0][colbase + r*8] = f2bf(acc[r]);
      }
    }
    __syncthreads();                               // the ONLY barrier per iteration
    // --- C: dwconv 3x3 + GELU gate from sb; next iter writes the other buffer ---
    {
      const int rg = threadIdx.x >> 5;             // output row 0..15
      const int px0 = (threadIdx.x & 31) * 8;
      float ax[8], ay[8];
      #pragma unroll
      for (int p = 0; p < 8; ++p) { ax[p] = 0.f; ay[p] = 0.f; }
      #pragma unroll
      for (int wr = 0; wr < 3; ++wr) {
        const u16* r1 = &sb[0][rg + wr][px0];
        const u16* r2 = &sb[1][rg + wr][px0];
        const s16x8 L1 = *(const s16x8*)r1, M1 = *(const s16x8*)(r1 + 8), R1 = *(const s16x8*)(r1 + 16);
        const s16x8 L2 = *(const s16x8*)r2, M2 = *(const s16x8*)(r2 + 8), R2 = *(const s16x8*)(r2 + 16);
        float cx[10], cy[10];
        cx[0] = bf2f((u16)L1[7]);  cy[0] = bf2f((u16)L2[7]);
        #pragma unroll
        for (int p = 0; p < 8; ++p) { cx[p+1] = bf2f((u16)M1[p]); cy[p+1] = bf2f((u16)M2[p]); }
        cx[9] = bf2f((u16)R1[0]);  cy[9] = bf2f((u16)R2[0]);
        const float w1a = wd1[wr*3+0], w1b = wd1[wr*3+1], w1c = wd1[wr*3+2];
        const float w2a = wd2[wr*3+0], w2b = wd2[wr*3+1], w2c = wd2[wr*3+2];
        #pragma unroll
        for (int p = 0; p < 8; ++p) {
          ax[p] += w1a*cx[p] + w1b*cx[p+1] + w1c*cx[p+2];
          ay[p] += w2a*cy[p] + w2b*cy[p+1] + w2c*cy[p+2];
        }
      }
      u32 pk[4];
      #pragma unroll
      for (int p2 = 0; p2 < 4; ++p2) {
        const float g0 = gelu(ax[2*p2])   * ay[2*p2];
        const float g1 = gelu(ax[2*p2+1]) * ay[2*p2+1];
        pk[p2] = (u32)f2bf(g0) | ((u32)f2bf(g1) << 16);
      }
      u16* gp = gbuf + (((size_t)(b*HID + c)) * BAND + (size_t)(sub*64 + it*16 + rg)) * WID + px0;
      *(uint4*)gp = make_uint4(pk[0], pk[1], pk[2], pk[3]);
    }
  }
}

// ------- K3b: project_out (170 -> 64) via MFMA -------
__global__ __launch_bounds__(256) void k_projout2(const u16* __restrict__ gbuf,
                                                  const u16* __restrict__ wof,
                                                  float* __restrict__ out, int hb) {
  const int b = blockIdx.x >> 7;
  const int p0 = (blockIdx.x & 127) << 8;
  const int w = threadIdx.x >> 6;
  const int lane = threadIdx.x & 63;
  const int lm = lane & 15, lh = lane >> 4;
  const size_t BW = (size_t)BAND * WID;
  const u16* gb = gbuf + (size_t)b * HID * BW + p0 + w*64 + lm;

  f32x4 acc[4][4];
  #pragma unroll
  for (int mt = 0; mt < 4; ++mt)
    #pragma unroll
    for (int ng = 0; ng < 4; ++ng)
      acc[mt][ng] = (f32x4){0.f,0.f,0.f,0.f};

  #pragma unroll
  for (int kc = 0; kc < 6; ++kc) {
    s16x8 A[4];
    #pragma unroll
    for (int mt = 0; mt < 4; ++mt)
      A[mt] = *(const s16x8*)(wof + ((mt*6 + kc)*64 + lane)*8);
    #pragma unroll
    for (int ng = 0; ng < 4; ++ng) {
      s16x8 Bf;
      #pragma unroll
      for (int r = 0; r < 8; ++r) {
        int c = kc*32 + lh*8 + r;
        if (kc == 5) c = min(c, HID - 1);
        Bf[r] = (short)gb[(size_t)c * BW + ng*16];
      }
      #pragma unroll
      for (int mt = 0; mt < 4; ++mt)
        acc[mt][ng] = __builtin_amdgcn_mfma_f32_16x16x32_bf16(A[mt], Bf, acc[mt][ng], 0,0,0);
    }
  }
  float* ob = out + (size_t)b * 64 * HW + (size_t)hb * WID + p0 + w*64 + lm;
  #pragma unroll
  for (int mt = 0; mt < 4; ++mt)
    #pragma unroll
    for (int ng = 0; ng < 4; ++ng)
      #pragma unroll
      for (int r = 0; r < 4; ++r)
        ob[(size_t)(mt*16 + lh*4 + r) * HW + ng*16] = acc[mt][ng][r];
}

extern "C" void kernel_launch(void* const* d_in, const int* in_sizes, int n_in,
                              void* d_out, int out_size, void* d_ws, size_t ws_size,
                              hipStream_t stream) {
  const float* x     = (const float*)d_in[0];
  const float* w_in  = (const float*)d_in[1];
  const float* w_dw  = (const float*)d_in[2];
  const float* fw    = (const float*)d_in[3];
  const float* w_out = (const float*)d_in[4];
  float* out = (float*)d_out;

  char* ws = (char*)d_ws;
  u16* mid    = (u16*)ws;                                  // 178,257,920 B (pre-conv)
  u16* gbuf   = (u16*)(ws + 178257920);                    // 44,564,480 B
  u16* wof    = (u16*)(ws + 178257920 + 44564480);         // 24,576 B
  u16* mfrag  = (u16*)(ws + 178257920 + 44564480 + 43520); // 2,785,280 B
  u16* wfrag  = (u16*)(ws + 178257920 + 44564480 + 43520 + 2785280); // 45,056 B

  k_prep<<<C2 + 2, 256, 0, stream>>>(w_in, w_out, fw, wfrag, wof, mfrag);
  k_projin2<<<NB*256, 256, 0, stream>>>(x, wfrag, mid);
  for (int sb = 0; sb < 2; ++sb) {
    const int hb = sb * BAND;
    k_pcgate<<<NB*HID*2, 512, 0, stream>>>(mid, mfrag, w_dw, gbuf, hb);
    k_projout2<<<NB*BAND, 256, 0, stream>>>(gbuf, wof, out, hb);
  }
}